// Round 2
// baseline (459.266 us; speedup 1.0000x reference)
//
#include <hip/hip_runtime.h>
#include <math.h>

#define Bn 8
#define Nn 262144
#define Kk 256
#define Dd 16
#define MCAP 4096
#define MSEL 1024
#define CHUNK 4096
#define ESTR 17   // LDS padding stride for per-seg embed sums (bank spread)
#define CSTR 20   // rep column stride: 80B, 16B-aligned for float4 stores

#define W_ATTR 1.0f
#define W_REP 1.0f
#define W_BPOS 10.0f
#define W_BNEG 3.0f
#define W_BBG 6.0f
#define W_MARG 10.0f
#define ALPHA_F 0.75f

// ---- workspace word offsets ----
// zero region: [0, ZERO_WORDS)
#define OFF_SUMF 0               // [B*K] f  sum focal (cp&valid)
#define OFF_CNT 2048             // [B*K] i  cp count per seg
#define OFF_INST 4096            // [B*K] i  instance size (valid points)
#define OFF_ESQ 6144             // [B*K] f  sum |e|^2
#define OFF_SCAL 8192            // [B*32]: 0 ce0n 1 rpos 2 rneg 3 ce0b 4 ncp 5 nbg
                                 //         6 mv(i) 7 ok(i) 8 beta_loss 9 rep_acc 10 attr
#define OFF_MODE 8448            // [1] i: 0 = 4-byte is_cp elements, 1 = byte elements
#define OFF_ESUM 8464            // [B*K*D] f  sum e (16B-aligned: 8464%4==0)
#define ZERO_WORDS (8464 + Bn*Kk*Dd)
#define OFF_FIRST ZERO_WORDS     // [B*K] i  min cp index, memset 0x7F -> 0x7F7F7F7F sentinel
#define OFF_CPIDX (OFF_FIRST + Bn*Kk)  // [B*MCAP] i (no init; guarded by mv)

// Detect is_cp element width. int32/float32 0/1 words are only {0,1,0x3F800000}.
// Byte layout yields words like 0x100/0x10000 for ~3/4 of set bytes -> thousands of hits.
__global__ void k_detect(const unsigned int* w, int* wsi) {
  int stride = gridDim.x * blockDim.x;
  int bad = 0;
  for (int i = blockIdx.x * blockDim.x + threadIdx.x; i < (Bn * Nn) / 4; i += stride) {
    unsigned int x = w[i];
    if (x > 1u && x != 0x3F800000u) bad = 1;
  }
  if (bad) atomicOr(&wsi[OFF_MODE], 1);
}

__global__ __launch_bounds__(256) void k_pass(const float* __restrict__ beta,
                                              const int* __restrict__ sid,
                                              const void* __restrict__ cpp,
                                              const float* __restrict__ embed,
                                              float* wsf, int* wsi) {
  const int b = blockIdx.y;
  const int tid = threadIdx.x;
  __shared__ float ls_esum[Kk * ESTR];
  __shared__ float ls_esq[Kk], ls_sumf[Kk];
  __shared__ int ls_inst[Kk], ls_cnt[Kk], ls_first[Kk];
  __shared__ float sred[4][8];
  for (int i = tid; i < Kk * ESTR; i += 256) ls_esum[i] = 0.f;
  ls_esq[tid] = 0.f; ls_sumf[tid] = 0.f;
  ls_inst[tid] = 0; ls_cnt[tid] = 0; ls_first[tid] = 0x7FFFFFFF;
  __syncthreads();
  const int mode = wsi[OFF_MODE];
  const int base = b * Nn;
  const float* eb = embed + (size_t)base * Dd;
  float a0 = 0.f, a1 = 0.f, a2 = 0.f, a3 = 0.f, a4 = 0.f, a5 = 0.f;
  for (int it = 0; it < CHUNK / 1024; ++it) {
    const int i0 = blockIdx.x * CHUNK + it * 1024 + tid * 4;
    int4 s4 = *(const int4*)(sid + base + i0);
    float4 b4 = *(const float4*)(beta + base + i0);
    unsigned int cpw[4];
    if (mode) {
      unsigned int u = ((const unsigned int*)cpp)[(base + i0) >> 2];
      cpw[0] = u & 0xffu; cpw[1] = (u >> 8) & 0xffu;
      cpw[2] = (u >> 16) & 0xffu; cpw[3] = u >> 24;
    } else {
      uint4 u = ((const uint4*)cpp)[(base + i0) >> 2];
      cpw[0] = u.x; cpw[1] = u.y; cpw[2] = u.z; cpw[3] = u.w;
    }
    const int ss[4] = {s4.x, s4.y, s4.z, s4.w};
    const float xs[4] = {b4.x, b4.y, b4.z, b4.w};
    #pragma unroll
    for (int j = 0; j < 4; ++j) {
      const int s = ss[j];
      const bool cp = cpw[j] != 0u;
      const float x = xs[j];
      const float p = 1.f / (1.f + __expf(-x));
      const float ax = fabsf(x);
      const float sp = __logf(1.f + __expf(-ax));
      const float ce0 = sp + fmaxf(x, 0.f);
      if (cp) { a1 += fmaxf(0.8f - p, 0.f); a4 += 1.f; }
      else    { a0 += ce0; a2 += fmaxf(p - 0.2f, 0.f); }
      if (s == -1) { a3 += ce0; a5 += 1.f; }
      if (s >= 0) {
        atomicAdd(&ls_inst[s], 1);
        const int i = i0 + j;
        const float4* e4 = (const float4*)(eb + (size_t)i * Dd);
        float4 v0 = e4[0], v1 = e4[1], v2 = e4[2], v3 = e4[3];
        float esq = v0.x*v0.x + v0.y*v0.y + v0.z*v0.z + v0.w*v0.w
                  + v1.x*v1.x + v1.y*v1.y + v1.z*v1.z + v1.w*v1.w
                  + v2.x*v2.x + v2.y*v2.y + v2.z*v2.z + v2.w*v2.w
                  + v3.x*v3.x + v3.y*v3.y + v3.z*v3.z + v3.w*v3.w;
        atomicAdd(&ls_esq[s], esq);
        float* es = &ls_esum[s * ESTR];
        atomicAdd(&es[0],  v0.x); atomicAdd(&es[1],  v0.y);
        atomicAdd(&es[2],  v0.z); atomicAdd(&es[3],  v0.w);
        atomicAdd(&es[4],  v1.x); atomicAdd(&es[5],  v1.y);
        atomicAdd(&es[6],  v1.z); atomicAdd(&es[7],  v1.w);
        atomicAdd(&es[8],  v2.x); atomicAdd(&es[9],  v2.y);
        atomicAdd(&es[10], v2.z); atomicAdd(&es[11], v2.w);
        atomicAdd(&es[12], v3.x); atomicAdd(&es[13], v3.y);
        atomicAdd(&es[14], v3.z); atomicAdd(&es[15], v3.w);
        if (cp) {
          const float ce1 = sp + fmaxf(-x, 0.f);
          const float om = 1.f - p;
          atomicAdd(&ls_sumf[s], ALPHA_F * om * om * ce1);
          atomicAdd(&ls_cnt[s], 1);
          atomicMin(&ls_first[s], i);
          int pos = atomicAdd(&wsi[OFF_SCAL + b * 32 + 6], 1);
          if (pos < MCAP) wsi[OFF_CPIDX + b * MCAP + pos] = i;
        }
      }
    }
  }
  __syncthreads();
  // merge per-segment LDS -> global
  atomicAdd(&wsf[OFF_SUMF + b * Kk + tid], ls_sumf[tid]);
  if (ls_cnt[tid]) atomicAdd(&wsi[OFF_CNT + b * Kk + tid], ls_cnt[tid]);
  atomicAdd(&wsi[OFF_INST + b * Kk + tid], ls_inst[tid]);
  atomicAdd(&wsf[OFF_ESQ + b * Kk + tid], ls_esq[tid]);
  atomicMin(&wsi[OFF_FIRST + b * Kk + tid], ls_first[tid]);
  #pragma unroll
  for (int d = 0; d < Dd; ++d)
    atomicAdd(&wsf[OFF_ESUM + ((size_t)b * Kk + tid) * Dd + d], ls_esum[tid * ESTR + d]);
  // block scalar reduce
  for (int o = 32; o > 0; o >>= 1) {
    a0 += __shfl_down(a0, o); a1 += __shfl_down(a1, o); a2 += __shfl_down(a2, o);
    a3 += __shfl_down(a3, o); a4 += __shfl_down(a4, o); a5 += __shfl_down(a5, o);
  }
  const int wv = tid >> 6;
  if ((tid & 63) == 0) {
    sred[wv][0] = a0; sred[wv][1] = a1; sred[wv][2] = a2;
    sred[wv][3] = a3; sred[wv][4] = a4; sred[wv][5] = a5;
  }
  __syncthreads();
  if (tid == 0) {
    float s0 = 0, s1 = 0, s2 = 0, s3 = 0, s4 = 0, s5 = 0;
    for (int q = 0; q < 4; ++q) {
      s0 += sred[q][0]; s1 += sred[q][1]; s2 += sred[q][2];
      s3 += sred[q][3]; s4 += sred[q][4]; s5 += sred[q][5];
    }
    atomicAdd(&wsf[OFF_SCAL + b * 32 + 0], s0);
    atomicAdd(&wsf[OFF_SCAL + b * 32 + 1], s1);
    atomicAdd(&wsf[OFF_SCAL + b * 32 + 2], s2);
    atomicAdd(&wsf[OFF_SCAL + b * 32 + 3], s3);
    atomicAdd(&wsf[OFF_SCAL + b * 32 + 4], s4);
    atomicAdd(&wsf[OFF_SCAL + b * 32 + 5], s5);
  }
}

__global__ __launch_bounds__(256) void k_event(const float* __restrict__ embed,
                                               float* wsf, int* wsi) {
  const int b = blockIdx.x;
  const int t = threadIdx.x;
  const int cnt = wsi[OFF_CNT + b * Kk + t];
  const int inst = wsi[OFF_INST + b * Kk + t];
  const float sumf = wsf[OFF_SUMF + b * Kk + t];
  const int fi = wsi[OFF_FIRST + b * Kk + t];
  const float esq = wsf[OFF_ESQ + b * Kk + t];
  const float4* ep = (const float4*)(wsf + OFF_ESUM + ((size_t)b * Kk + t) * Dd);
  float4 S0 = ep[0], S1 = ep[1], S2 = ep[2], S3 = ep[3];
  const bool has = cnt > 0;
  float attr_p = 0.f, w = 0.f, wf = 0.f;
  if (has) {
    const float4* a4 = (const float4*)(embed + ((size_t)b * Nn + (size_t)fi) * Dd);
    float4 A0 = a4[0], A1 = a4[1], A2 = a4[2], A3 = a4[3];
    float asq = A0.x*A0.x + A0.y*A0.y + A0.z*A0.z + A0.w*A0.w
              + A1.x*A1.x + A1.y*A1.y + A1.z*A1.z + A1.w*A1.w
              + A2.x*A2.x + A2.y*A2.y + A2.z*A2.z + A2.w*A2.w
              + A3.x*A3.x + A3.y*A3.y + A3.z*A3.z + A3.w*A3.w;
    float ad = A0.x*S0.x + A0.y*S0.y + A0.z*S0.z + A0.w*S0.w
             + A1.x*S1.x + A1.y*S1.y + A1.z*S1.z + A1.w*S1.w
             + A2.x*S2.x + A2.y*S2.y + A2.z*S2.z + A2.w*S2.w
             + A3.x*S3.x + A3.y*S3.y + A3.z*S3.z + A3.w*S3.w;
    const float instf = (float)inst;
    const float d2s = esq - 2.f * ad + instf * asq;
    attr_p = d2s / fmaxf(instf, 1.f);
    w = instf;
    wf = instf * (sumf / fmaxf((float)cnt, 1.f));
  }
  for (int o = 32; o > 0; o >>= 1) {
    attr_p += __shfl_down(attr_p, o);
    w += __shfl_down(w, o);
    wf += __shfl_down(wf, o);
  }
  __shared__ float r3[3][4];
  if ((t & 63) == 0) { r3[0][t >> 6] = attr_p; r3[1][t >> 6] = w; r3[2][t >> 6] = wf; }
  __syncthreads();
  if (t == 0) {
    float at = r3[0][0] + r3[0][1] + r3[0][2] + r3[0][3];
    float sw = r3[1][0] + r3[1][1] + r3[1][2] + r3[1][3];
    float swf = r3[2][0] + r3[2][1] + r3[2][2] + r3[2][3];
    float pos_bce = swf / fmaxf(sw, 1.f);
    float* sc = wsf + OFF_SCAL + b * 32;
    float ce0n = sc[0], rpos = sc[1], rneg = sc[2], ce0b = sc[3], ncp = sc[4], nbg = sc[5];
    int mv = wsi[OFF_SCAL + b * 32 + 6];
    float nncp = (float)Nn - ncp;
    float neg_bce = nncp > 0.f ? ce0n / fmaxf(nncp, 1.f) : 0.f;
    float pos_m = rpos / fmaxf(ncp, 1.f);
    float neg_m = nncp > 0.f ? rneg / fmaxf(nncp, 1.f) : 0.f;
    float bg_bce = nbg > 0.f ? ce0b / fmaxf(nbg, 1.f) : 0.f;
    sc[8] = W_BPOS * pos_bce + W_BNEG * neg_bce + W_BBG * bg_bce + W_MARG * (pos_m + neg_m);
    sc[10] = at;
    float nvalid = (float)Nn - nbg;
    wsi[OFF_SCAL + b * 32 + 7] = (nvalid > 0.f && mv > 0) ? 1 : 0;
  }
}

__global__ __launch_bounds__(256) void k_rep(const float* __restrict__ embed,
                                             float* wsf, int* wsi) {
  const int b = blockIdx.y;
  const int t = threadIdx.x;
  __shared__ int sidx[MCAP];
  __shared__ float cemb[256 * CSTR];
  __shared__ float csq[256];
  __shared__ float red[4];
  const int mv = wsi[OFF_SCAL + b * 32 + 6];
  const int msel = mv < MSEL ? mv : MSEL;
  const int mload = mv < MCAP ? mv : MCAP;
  for (int i = t; i < MCAP; i += 256)
    sidx[i] = (i < mload) ? wsi[OFF_CPIDX + b * MCAP + i] : 0x7FFFFFFF;
  __syncthreads();
  if (mv > MSEL) {
    // rare path: bitonic sort -> smallest-index selection (never triggers at Mv~262)
    for (int ksz = 2; ksz <= MCAP; ksz <<= 1) {
      for (int j = ksz >> 1; j > 0; j >>= 1) {
        for (int e = t; e < MCAP; e += 256) {
          int ixj = e ^ j;
          if (ixj > e) {
            bool up = ((e & ksz) == 0);
            int x = sidx[e], y = sidx[ixj];
            if ((x > y) == up) { sidx[e] = y; sidx[ixj] = x; }
          }
        }
        __syncthreads();
      }
    }
  }
  const float* eb = embed + (size_t)b * Nn * Dd;
  const int row = blockIdx.x * 64 + (t & 63);
  const int cg = t >> 6;   // all 64 lanes of a wave share cg -> LDS broadcast reads
  const bool rok = row < msel;
  float r[Dd];
  float rsq = 0.f;
  if (rok) {
    const float4* s = (const float4*)(eb + (size_t)sidx[row] * Dd);
    float4 v0 = s[0], v1 = s[1], v2 = s[2], v3 = s[3];
    r[0]=v0.x; r[1]=v0.y; r[2]=v0.z; r[3]=v0.w;
    r[4]=v1.x; r[5]=v1.y; r[6]=v1.z; r[7]=v1.w;
    r[8]=v2.x; r[9]=v2.y; r[10]=v2.z; r[11]=v2.w;
    r[12]=v3.x; r[13]=v3.y; r[14]=v3.z; r[15]=v3.w;
    #pragma unroll
    for (int d = 0; d < Dd; ++d) rsq += r[d] * r[d];
  }
  float acc = 0.f;
  for (int c0 = 0; c0 < msel; c0 += 256) {
    const int nc = (msel - c0) < 256 ? (msel - c0) : 256;
    __syncthreads();
    for (int wvi = t; wvi < nc * 4; wvi += 256) {
      int col = wvi >> 2, q = wvi & 3;
      float4 v = ((const float4*)(eb + (size_t)sidx[c0 + col] * Dd))[q];
      *(float4*)&cemb[col * CSTR + q * 4] = v;
    }
    __syncthreads();
    for (int col = t; col < nc; col += 256) {
      float s = 0.f;
      #pragma unroll
      for (int d = 0; d < Dd; ++d) s += cemb[col * CSTR + d] * cemb[col * CSTR + d];
      csq[col] = s;
    }
    __syncthreads();
    if (rok) {
      for (int c = cg; c < nc; c += 4) {
        float dotrc = 0.f;
        #pragma unroll
        for (int d = 0; d < Dd; ++d) dotrc += r[d] * cemb[c * CSTR + d];
        acc += __expf(2.f * dotrc - rsq - csq[c]);
      }
    }
  }
  for (int o = 32; o > 0; o >>= 1) acc += __shfl_down(acc, o);
  if ((t & 63) == 0) red[t >> 6] = acc;
  __syncthreads();
  if (t == 0) {
    float s = red[0] + red[1] + red[2] + red[3];
    if (s != 0.f) atomicAdd(&wsf[OFF_SCAL + b * 32 + 9], s);
  }
}

__global__ void k_final(float* wsf, int* wsi, float* out, int out_size) {
  const int t = threadIdx.x;
  if (t == 0) {
    float total = 0.f;
    int cnt = 0;
    for (int b = 0; b < Bn; ++b) {
      float* sc = wsf + OFF_SCAL + b * 32;
      int* sci = wsi + OFF_SCAL + b * 32;
      int mv = sci[6];
      if (sci[7]) {
        float mvf = (float)mv;
        float rep = (mv > 1) ? W_REP * sc[9] / fmaxf(mvf * mvf, 1.f) : 0.f;
        total += sc[8] + W_ATTR * sc[10] + rep;
        cnt++;
      }
    }
    out[0] = (cnt > 0) ? total / (float)cnt : 0.f;
  }
  for (int i = 1 + t; i < out_size; i += 256) out[i] = 0.f;
}

extern "C" void kernel_launch(void* const* d_in, const int* in_sizes, int n_in,
                              void* d_out, int out_size, void* d_ws, size_t ws_size,
                              hipStream_t stream) {
  const float* beta = (const float*)d_in[0];
  const float* embed = (const float*)d_in[1];
  const int* sid = (const int*)d_in[2];
  const void* cp = d_in[3];
  float* out = (float*)d_out;
  float* wsf = (float*)d_ws;
  int* wsi = (int*)d_ws;

  hipMemsetAsync(d_ws, 0, (size_t)ZERO_WORDS * 4, stream);
  hipMemsetAsync((char*)d_ws + (size_t)OFF_FIRST * 4, 0x7F, (size_t)Bn * Kk * 4, stream);
  k_detect<<<256, 256, 0, stream>>>((const unsigned int*)cp, wsi);
  dim3 gp(Nn / CHUNK, Bn);
  k_pass<<<gp, 256, 0, stream>>>(beta, sid, cp, embed, wsf, wsi);
  k_event<<<Bn, 256, 0, stream>>>(embed, wsf, wsi);
  dim3 gr(MSEL / 64, Bn);
  k_rep<<<gr, 256, 0, stream>>>(embed, wsf, wsi);
  k_final<<<1, 256, 0, stream>>>(wsf, wsi, out, out_size);
}

// Round 3
// 407.155 us; speedup vs baseline: 1.1280x; 1.1280x over previous
//
#include <hip/hip_runtime.h>
#include <math.h>

#define Bn 8
#define Nn 262144
#define Kk 256
#define Dd 16
#define MCAP 4096
#define MSEL 1024
#define CHUNK 2048
#define NCH (Nn / CHUNK)   // 128 chunks per event
#define ESTR 17            // LDS padding stride for per-seg embed sums
#define CSTR 20            // rep column stride (80B, float4-aligned)
#define PSTR 20            // partial record stride in words (80B, float4-aligned)

#define W_ATTR 1.0f
#define W_REP 1.0f
#define W_BPOS 10.0f
#define W_BNEG 3.0f
#define W_BBG 6.0f
#define W_MARG 10.0f
#define ALPHA_F 0.75f

// ---- workspace word offsets ----
#define OFF_SUMF 0                      // [B*K] f  sum focal (atomic, cp-only)
#define OFF_CNT 2048                    // [B*K] i  cp count  (atomic, cp-only)
#define OFF_INST 4096                   // [B*K] i  instance size (from reducer)
#define OFF_ESQ 6144                    // [B*K] f  sum |e|^2      (from reducer)
#define OFF_SCAL 8192                   // [B*32] scalars
#define OFF_MODE 8448                   // [1] i: is_cp element width flag
#define OFF_ESUM 8464                   // [B*K*D] f sum e         (from reducer)
#define ZERO_WORDS (8464 + Bn*Kk*Dd)    // 41232 words (covers fallback atomics too)
#define OFF_FIRST ZERO_WORDS            // [B*K] i, memset 0x7F
#define OFF_CPIDX (OFF_FIRST + Bn*Kk)   // [B*MCAP] i
#define OFF_PART (OFF_CPIDX + Bn*MCAP)  // [B*NCH*K*PSTR] f  per-block partials
#define PART_WORDS ((size_t)Bn * NCH * Kk * PSTR)
#define WS_NEEDED (((size_t)OFF_PART + PART_WORDS) * 4)

// Detect is_cp element width. int32/float32 0/1 words are only {0,1,0x3F800000};
// a packed-byte layout yields other word values for most set bytes.
__global__ void k_detect(const unsigned int* w, int* wsi) {
  int stride = gridDim.x * blockDim.x;
  int bad = 0;
  for (int i = blockIdx.x * blockDim.x + threadIdx.x; i < (Bn * Nn) / 4; i += stride) {
    unsigned int x = w[i];
    if (x > 1u && x != 0x3F800000u) bad = 1;
  }
  if (bad) atomicOr(&wsi[OFF_MODE], 1);
}

__global__ __launch_bounds__(256) void k_pass(const float* __restrict__ beta,
                                              const int* __restrict__ sid,
                                              const void* __restrict__ cpp,
                                              const float* __restrict__ embed,
                                              float* wsf, int* wsi, int use_part) {
  const int b = blockIdx.y;
  const int ch = blockIdx.x;
  const int tid = threadIdx.x;
  __shared__ float ls_esum[Kk * ESTR];
  __shared__ float ls_esq[Kk], ls_sumf[Kk];
  __shared__ int ls_inst[Kk], ls_cnt[Kk], ls_first[Kk];
  __shared__ float sred[4][8];
  for (int i = tid; i < Kk * ESTR; i += 256) ls_esum[i] = 0.f;
  ls_esq[tid] = 0.f; ls_sumf[tid] = 0.f;
  ls_inst[tid] = 0; ls_cnt[tid] = 0; ls_first[tid] = 0x7FFFFFFF;
  __syncthreads();
  const int mode = wsi[OFF_MODE];
  const int base = b * Nn;
  const float* eb = embed + (size_t)base * Dd;
  float a0 = 0.f, a1 = 0.f, a2 = 0.f, a3 = 0.f, a4 = 0.f, a5 = 0.f;
  for (int it = 0; it < CHUNK / 1024; ++it) {
    const int i0 = ch * CHUNK + it * 1024 + tid * 4;
    // issue ALL loads for this iteration up front (no data-dependent gating)
    int4 s4 = *(const int4*)(sid + base + i0);
    float4 b4 = *(const float4*)(beta + base + i0);
    unsigned int cpw[4];
    if (mode) {
      unsigned int u = ((const unsigned int*)cpp)[(base + i0) >> 2];
      cpw[0] = u & 0xffu; cpw[1] = (u >> 8) & 0xffu;
      cpw[2] = (u >> 16) & 0xffu; cpw[3] = u >> 24;
    } else {
      uint4 u = ((const uint4*)cpp)[(base + i0) >> 2];
      cpw[0] = u.x; cpw[1] = u.y; cpw[2] = u.z; cpw[3] = u.w;
    }
    float4 ev[16];
    #pragma unroll
    for (int q = 0; q < 16; ++q)
      ev[q] = *(const float4*)(eb + (size_t)(i0 + (q >> 2)) * Dd + (q & 3) * 4);
    const int ss[4] = {s4.x, s4.y, s4.z, s4.w};
    const float xs[4] = {b4.x, b4.y, b4.z, b4.w};
    #pragma unroll
    for (int j = 0; j < 4; ++j) {
      const int s = ss[j];
      const bool cp = cpw[j] != 0u;
      const float x = xs[j];
      const float p = 1.f / (1.f + __expf(-x));
      const float ax = fabsf(x);
      const float sp = __logf(1.f + __expf(-ax));
      const float ce0 = sp + fmaxf(x, 0.f);
      if (cp) { a1 += fmaxf(0.8f - p, 0.f); a4 += 1.f; }
      else    { a0 += ce0; a2 += fmaxf(p - 0.2f, 0.f); }
      if (s == -1) { a3 += ce0; a5 += 1.f; }
      if (s >= 0) {
        atomicAdd(&ls_inst[s], 1);
        float4 v0 = ev[j * 4], v1 = ev[j * 4 + 1], v2 = ev[j * 4 + 2], v3 = ev[j * 4 + 3];
        float esq = v0.x*v0.x + v0.y*v0.y + v0.z*v0.z + v0.w*v0.w
                  + v1.x*v1.x + v1.y*v1.y + v1.z*v1.z + v1.w*v1.w
                  + v2.x*v2.x + v2.y*v2.y + v2.z*v2.z + v2.w*v2.w
                  + v3.x*v3.x + v3.y*v3.y + v3.z*v3.z + v3.w*v3.w;
        atomicAdd(&ls_esq[s], esq);
        float* es = &ls_esum[s * ESTR];
        atomicAdd(&es[0],  v0.x); atomicAdd(&es[1],  v0.y);
        atomicAdd(&es[2],  v0.z); atomicAdd(&es[3],  v0.w);
        atomicAdd(&es[4],  v1.x); atomicAdd(&es[5],  v1.y);
        atomicAdd(&es[6],  v1.z); atomicAdd(&es[7],  v1.w);
        atomicAdd(&es[8],  v2.x); atomicAdd(&es[9],  v2.y);
        atomicAdd(&es[10], v2.z); atomicAdd(&es[11], v2.w);
        atomicAdd(&es[12], v3.x); atomicAdd(&es[13], v3.y);
        atomicAdd(&es[14], v3.z); atomicAdd(&es[15], v3.w);
        if (cp) {
          const int i = i0 + j;
          const float ce1 = sp + fmaxf(-x, 0.f);
          const float om = 1.f - p;
          atomicAdd(&ls_sumf[s], ALPHA_F * om * om * ce1);
          atomicAdd(&ls_cnt[s], 1);
          atomicMin(&ls_first[s], i);
          int pos = atomicAdd(&wsi[OFF_SCAL + b * 32 + 6], 1);
          if (pos < MCAP) wsi[OFF_CPIDX + b * MCAP + pos] = i;
        }
      }
    }
  }
  __syncthreads();
  // rare (cp-only) stats: global atomics are fine
  if (ls_cnt[tid]) {
    atomicAdd(&wsf[OFF_SUMF + b * Kk + tid], ls_sumf[tid]);
    atomicAdd(&wsi[OFF_CNT + b * Kk + tid], ls_cnt[tid]);
    atomicMin(&wsi[OFF_FIRST + b * Kk + tid], ls_first[tid]);
  }
  // heavy stats: per-block partial record (plain streaming stores)
  if (use_part) {
    float* pb = wsf + OFF_PART + (((size_t)(b * NCH + ch)) * Kk + tid) * PSTR;
    const float* es = &ls_esum[tid * ESTR];
    *(float4*)&pb[0]  = make_float4(es[0],  es[1],  es[2],  es[3]);
    *(float4*)&pb[4]  = make_float4(es[4],  es[5],  es[6],  es[7]);
    *(float4*)&pb[8]  = make_float4(es[8],  es[9],  es[10], es[11]);
    *(float4*)&pb[12] = make_float4(es[12], es[13], es[14], es[15]);
    pb[16] = ls_esq[tid];
    pb[17] = (float)ls_inst[tid];
  } else {
    // fallback if ws too small: atomic merge (slow but correct)
    atomicAdd(&wsf[OFF_ESQ + b * Kk + tid], ls_esq[tid]);
    atomicAdd(&wsi[OFF_INST + b * Kk + tid], ls_inst[tid]);
    #pragma unroll
    for (int d = 0; d < Dd; ++d)
      atomicAdd(&wsf[OFF_ESUM + ((size_t)b * Kk + tid) * Dd + d], ls_esum[tid * ESTR + d]);
  }
  // block scalar reduce
  for (int o = 32; o > 0; o >>= 1) {
    a0 += __shfl_down(a0, o); a1 += __shfl_down(a1, o); a2 += __shfl_down(a2, o);
    a3 += __shfl_down(a3, o); a4 += __shfl_down(a4, o); a5 += __shfl_down(a5, o);
  }
  const int wv = tid >> 6;
  if ((tid & 63) == 0) {
    sred[wv][0] = a0; sred[wv][1] = a1; sred[wv][2] = a2;
    sred[wv][3] = a3; sred[wv][4] = a4; sred[wv][5] = a5;
  }
  __syncthreads();
  if (tid == 0) {
    float s0 = 0, s1 = 0, s2 = 0, s3 = 0, s4 = 0, s5 = 0;
    for (int q = 0; q < 4; ++q) {
      s0 += sred[q][0]; s1 += sred[q][1]; s2 += sred[q][2];
      s3 += sred[q][3]; s4 += sred[q][4]; s5 += sred[q][5];
    }
    atomicAdd(&wsf[OFF_SCAL + b * 32 + 0], s0);
    atomicAdd(&wsf[OFF_SCAL + b * 32 + 1], s1);
    atomicAdd(&wsf[OFF_SCAL + b * 32 + 2], s2);
    atomicAdd(&wsf[OFF_SCAL + b * 32 + 3], s3);
    atomicAdd(&wsf[OFF_SCAL + b * 32 + 4], s4);
    atomicAdd(&wsf[OFF_SCAL + b * 32 + 5], s5);
  }
}

// tree-reduce the per-block partials: esum (one thread per b,seg,d),
// esq/inst (threads g < B*K double-duty)
__global__ __launch_bounds__(256) void k_reduce(float* wsf, int* wsi) {
  const int g = blockIdx.x * 256 + threadIdx.x;   // [0, B*K*D) = 32768
  {
    const int b = g >> 12;
    const int seg = (g >> 4) & 255;
    const int d = g & 15;
    const float* p = wsf + OFF_PART + ((size_t)b * NCH * Kk + seg) * PSTR + d;
    float s = 0.f;
    for (int chh = 0; chh < NCH; ++chh) s += p[(size_t)chh * Kk * PSTR];
    wsf[OFF_ESUM + ((size_t)((b << 8) + seg)) * Dd + d] = s;
  }
  if (g < Bn * Kk) {
    const int b = g >> 8, seg = g & 255;
    const float* p = wsf + OFF_PART + ((size_t)b * NCH * Kk + seg) * PSTR;
    float sq = 0.f, si = 0.f;
    for (int chh = 0; chh < NCH; ++chh) {
      sq += p[(size_t)chh * Kk * PSTR + 16];
      si += p[(size_t)chh * Kk * PSTR + 17];
    }
    wsf[OFF_ESQ + g] = sq;
    wsi[OFF_INST + g] = (int)(si + 0.5f);
  }
}

__global__ __launch_bounds__(256) void k_event(const float* __restrict__ embed,
                                               float* wsf, int* wsi) {
  const int b = blockIdx.x;
  const int t = threadIdx.x;
  const int cnt = wsi[OFF_CNT + b * Kk + t];
  const int inst = wsi[OFF_INST + b * Kk + t];
  const float sumf = wsf[OFF_SUMF + b * Kk + t];
  const int fi = wsi[OFF_FIRST + b * Kk + t];
  const float esq = wsf[OFF_ESQ + b * Kk + t];
  const float4* ep = (const float4*)(wsf + OFF_ESUM + ((size_t)b * Kk + t) * Dd);
  float4 S0 = ep[0], S1 = ep[1], S2 = ep[2], S3 = ep[3];
  const bool has = cnt > 0;
  float attr_p = 0.f, w = 0.f, wf = 0.f;
  if (has) {
    const float4* a4 = (const float4*)(embed + ((size_t)b * Nn + (size_t)fi) * Dd);
    float4 A0 = a4[0], A1 = a4[1], A2 = a4[2], A3 = a4[3];
    float asq = A0.x*A0.x + A0.y*A0.y + A0.z*A0.z + A0.w*A0.w
              + A1.x*A1.x + A1.y*A1.y + A1.z*A1.z + A1.w*A1.w
              + A2.x*A2.x + A2.y*A2.y + A2.z*A2.z + A2.w*A2.w
              + A3.x*A3.x + A3.y*A3.y + A3.z*A3.z + A3.w*A3.w;
    float ad = A0.x*S0.x + A0.y*S0.y + A0.z*S0.z + A0.w*S0.w
             + A1.x*S1.x + A1.y*S1.y + A1.z*S1.z + A1.w*S1.w
             + A2.x*S2.x + A2.y*S2.y + A2.z*S2.z + A2.w*S2.w
             + A3.x*S3.x + A3.y*S3.y + A3.z*S3.z + A3.w*S3.w;
    const float instf = (float)inst;
    const float d2s = esq - 2.f * ad + instf * asq;
    attr_p = d2s / fmaxf(instf, 1.f);
    w = instf;
    wf = instf * (sumf / fmaxf((float)cnt, 1.f));
  }
  for (int o = 32; o > 0; o >>= 1) {
    attr_p += __shfl_down(attr_p, o);
    w += __shfl_down(w, o);
    wf += __shfl_down(wf, o);
  }
  __shared__ float r3[3][4];
  if ((t & 63) == 0) { r3[0][t >> 6] = attr_p; r3[1][t >> 6] = w; r3[2][t >> 6] = wf; }
  __syncthreads();
  if (t == 0) {
    float at = r3[0][0] + r3[0][1] + r3[0][2] + r3[0][3];
    float sw = r3[1][0] + r3[1][1] + r3[1][2] + r3[1][3];
    float swf = r3[2][0] + r3[2][1] + r3[2][2] + r3[2][3];
    float pos_bce = swf / fmaxf(sw, 1.f);
    float* sc = wsf + OFF_SCAL + b * 32;
    float ce0n = sc[0], rpos = sc[1], rneg = sc[2], ce0b = sc[3], ncp = sc[4], nbg = sc[5];
    int mv = wsi[OFF_SCAL + b * 32 + 6];
    float nncp = (float)Nn - ncp;
    float neg_bce = nncp > 0.f ? ce0n / fmaxf(nncp, 1.f) : 0.f;
    float pos_m = rpos / fmaxf(ncp, 1.f);
    float neg_m = nncp > 0.f ? rneg / fmaxf(nncp, 1.f) : 0.f;
    float bg_bce = nbg > 0.f ? ce0b / fmaxf(nbg, 1.f) : 0.f;
    sc[8] = W_BPOS * pos_bce + W_BNEG * neg_bce + W_BBG * bg_bce + W_MARG * (pos_m + neg_m);
    sc[10] = at;
    float nvalid = (float)Nn - nbg;
    wsi[OFF_SCAL + b * 32 + 7] = (nvalid > 0.f && mv > 0) ? 1 : 0;
  }
}

__global__ __launch_bounds__(256) void k_rep(const float* __restrict__ embed,
                                             float* wsf, int* wsi) {
  const int b = blockIdx.y;
  const int t = threadIdx.x;
  __shared__ int sidx[MCAP];
  __shared__ float cemb[256 * CSTR];
  __shared__ float csq[256];
  __shared__ float red[4];
  const int mv = wsi[OFF_SCAL + b * 32 + 6];
  const int msel = mv < MSEL ? mv : MSEL;
  const int mload = mv < MCAP ? mv : MCAP;
  for (int i = t; i < MCAP; i += 256)
    sidx[i] = (i < mload) ? wsi[OFF_CPIDX + b * MCAP + i] : 0x7FFFFFFF;
  __syncthreads();
  if (mv > MSEL) {
    for (int ksz = 2; ksz <= MCAP; ksz <<= 1) {
      for (int j = ksz >> 1; j > 0; j >>= 1) {
        for (int e = t; e < MCAP; e += 256) {
          int ixj = e ^ j;
          if (ixj > e) {
            bool up = ((e & ksz) == 0);
            int x = sidx[e], y = sidx[ixj];
            if ((x > y) == up) { sidx[e] = y; sidx[ixj] = x; }
          }
        }
        __syncthreads();
      }
    }
  }
  const float* eb = embed + (size_t)b * Nn * Dd;
  const int row = blockIdx.x * 64 + (t & 63);
  const int cg = t >> 6;
  const bool rok = row < msel;
  float r[Dd];
  float rsq = 0.f;
  if (rok) {
    const float4* s = (const float4*)(eb + (size_t)sidx[row] * Dd);
    float4 v0 = s[0], v1 = s[1], v2 = s[2], v3 = s[3];
    r[0]=v0.x; r[1]=v0.y; r[2]=v0.z; r[3]=v0.w;
    r[4]=v1.x; r[5]=v1.y; r[6]=v1.z; r[7]=v1.w;
    r[8]=v2.x; r[9]=v2.y; r[10]=v2.z; r[11]=v2.w;
    r[12]=v3.x; r[13]=v3.y; r[14]=v3.z; r[15]=v3.w;
    #pragma unroll
    for (int d = 0; d < Dd; ++d) rsq += r[d] * r[d];
  }
  float acc = 0.f;
  for (int c0 = 0; c0 < msel; c0 += 256) {
    const int nc = (msel - c0) < 256 ? (msel - c0) : 256;
    __syncthreads();
    for (int wvi = t; wvi < nc * 4; wvi += 256) {
      int col = wvi >> 2, q = wvi & 3;
      float4 v = ((const float4*)(eb + (size_t)sidx[c0 + col] * Dd))[q];
      *(float4*)&cemb[col * CSTR + q * 4] = v;
    }
    __syncthreads();
    for (int col = t; col < nc; col += 256) {
      float s = 0.f;
      #pragma unroll
      for (int d = 0; d < Dd; ++d) s += cemb[col * CSTR + d] * cemb[col * CSTR + d];
      csq[col] = s;
    }
    __syncthreads();
    if (rok) {
      for (int c = cg; c < nc; c += 4) {
        float dotrc = 0.f;
        #pragma unroll
        for (int d = 0; d < Dd; ++d) dotrc += r[d] * cemb[c * CSTR + d];
        acc += __expf(2.f * dotrc - rsq - csq[c]);
      }
    }
  }
  for (int o = 32; o > 0; o >>= 1) acc += __shfl_down(acc, o);
  if ((t & 63) == 0) red[t >> 6] = acc;
  __syncthreads();
  if (t == 0) {
    float s = red[0] + red[1] + red[2] + red[3];
    if (s != 0.f) atomicAdd(&wsf[OFF_SCAL + b * 32 + 9], s);
  }
}

__global__ void k_final(float* wsf, int* wsi, float* out, int out_size) {
  const int t = threadIdx.x;
  if (t == 0) {
    float total = 0.f;
    int cnt = 0;
    for (int b = 0; b < Bn; ++b) {
      float* sc = wsf + OFF_SCAL + b * 32;
      int* sci = wsi + OFF_SCAL + b * 32;
      int mv = sci[6];
      if (sci[7]) {
        float mvf = (float)mv;
        float rep = (mv > 1) ? W_REP * sc[9] / fmaxf(mvf * mvf, 1.f) : 0.f;
        total += sc[8] + W_ATTR * sc[10] + rep;
        cnt++;
      }
    }
    out[0] = (cnt > 0) ? total / (float)cnt : 0.f;
  }
  for (int i = 1 + t; i < out_size; i += 256) out[i] = 0.f;
}

extern "C" void kernel_launch(void* const* d_in, const int* in_sizes, int n_in,
                              void* d_out, int out_size, void* d_ws, size_t ws_size,
                              hipStream_t stream) {
  const float* beta = (const float*)d_in[0];
  const float* embed = (const float*)d_in[1];
  const int* sid = (const int*)d_in[2];
  const void* cp = d_in[3];
  float* out = (float*)d_out;
  float* wsf = (float*)d_ws;
  int* wsi = (int*)d_ws;
  const int use_part = ws_size >= WS_NEEDED ? 1 : 0;

  hipMemsetAsync(d_ws, 0, (size_t)ZERO_WORDS * 4, stream);
  hipMemsetAsync((char*)d_ws + (size_t)OFF_FIRST * 4, 0x7F, (size_t)Bn * Kk * 4, stream);
  k_detect<<<256, 256, 0, stream>>>((const unsigned int*)cp, wsi);
  dim3 gp(NCH, Bn);
  k_pass<<<gp, 256, 0, stream>>>(beta, sid, cp, embed, wsf, wsi, use_part);
  if (use_part) k_reduce<<<(Bn * Kk * Dd) / 256, 256, 0, stream>>>(wsf, wsi);
  k_event<<<Bn, 256, 0, stream>>>(embed, wsf, wsi);
  dim3 gr(MSEL / 64, Bn);
  k_rep<<<gr, 256, 0, stream>>>(embed, wsf, wsi);
  k_final<<<1, 256, 0, stream>>>(wsf, wsi, out, out_size);
}

// Round 4
// 264.506 us; speedup vs baseline: 1.7363x; 1.5393x over previous
//
#include <hip/hip_runtime.h>
#include <math.h>

#define Bn 8
#define Nn 262144
#define Kk 256
#define Dd 16
#define MCAP 4096
#define MSEL 1024
#define CHUNK 2048
#define NCH (Nn / CHUNK)   // 128 chunks per event
#define ASTR 20            // anchor LDS row stride in words (80B, float4-aligned; 8 disjoint bank-slots)
#define CSTR 20            // rep column stride

#define W_ATTR 1.0f
#define W_REP 1.0f
#define W_BPOS 10.0f
#define W_BNEG 3.0f
#define W_BBG 6.0f
#define W_MARG 10.0f
#define ALPHA_F 0.75f

// ---- workspace word offsets ----
#define OFF_SUMF 0                       // [B*K] f  sum focal   (k_cplist, atomic)
#define OFF_CNT 2048                     // [B*K] i  cp count    (k_cplist, atomic)
#define OFF_INST 4096                    // [B*K] i  instance size (k_reduce)
#define OFF_D2 6144                      // [B*K] f  sum d2        (k_reduce)
#define OFF_SCAL 8192                    // [B*32] scalars: 0 ce0n 1 rpos 2 rneg 3 ce0b 4 ncp 5 nbg
                                         //                 6 mv(i) 7 ok(i) 8 beta_loss 9 rep_acc 10 attr
#define OFF_MODE 8448                    // [1] i: is_cp element width flag
#define ZERO_WORDS 8452
#define OFF_FIRST 8464                   // [B*K] i  min cp index, memset 0x7F
#define OFF_ANCH (OFF_FIRST + Bn*Kk)     // [B*K*D] f anchor table (k_anchor writes ALL rows)
#define OFF_CPIDX (OFF_ANCH + Bn*Kk*Dd)  // [B*MCAP] i
#define OFF_PART (OFF_CPIDX + Bn*MCAP)   // [B*NCH*K*2] f per-block {d2, inst}
#define PART_WORDS ((size_t)Bn * NCH * Kk * 2)
#define WS_NEEDED (((size_t)OFF_PART + PART_WORDS) * 4)

// Detect is_cp element width (int32/float32 0-1 words are only {0,1,0x3F800000}).
__global__ void k_detect(const unsigned int* w, int* wsi) {
  int stride = gridDim.x * blockDim.x;
  int bad = 0;
  for (int i = blockIdx.x * blockDim.x + threadIdx.x; i < (Bn * Nn) / 4; i += stride) {
    unsigned int x = w[i];
    if (x > 1u && x != 0x3F800000u) bad = 1;
  }
  if (bad) atomicOr(&wsi[OFF_MODE], 1);
}

// Handle all cp-only stats: focal sum, cp count, first index, cp-index list.
// ~2100 hits over 2.1M points -> global atomics are cheap here.
__global__ __launch_bounds__(256) void k_cplist(const float* __restrict__ beta,
                                                const int* __restrict__ sid,
                                                const void* __restrict__ cpp,
                                                float* wsf, int* wsi) {
  const int mode = wsi[OFF_MODE];
  const int stride = gridDim.x * blockDim.x;
  for (int i = blockIdx.x * blockDim.x + threadIdx.x; i < Bn * Nn; i += stride) {
    bool cp = mode ? (((const unsigned char*)cpp)[i] != 0)
                   : (((const unsigned int*)cpp)[i] != 0u);
    if (cp) {
      const int b = i >> 18;          // i / Nn
      const int ii = i & (Nn - 1);    // event-local index
      const int s = sid[i];
      if (s >= 0) {
        const float x = beta[i];
        const float p = 1.f / (1.f + __expf(-x));
        const float sp = __logf(1.f + __expf(-fabsf(x)));
        const float ce1 = sp + fmaxf(-x, 0.f);
        const float om = 1.f - p;
        atomicAdd(&wsf[OFF_SUMF + b * Kk + s], ALPHA_F * om * om * ce1);
        atomicAdd(&wsi[OFF_CNT + b * Kk + s], 1);
        atomicMin(&wsi[OFF_FIRST + b * Kk + s], ii);
        int pos = atomicAdd(&wsi[OFF_SCAL + b * 32 + 6], 1);
        if (pos < MCAP) wsi[OFF_CPIDX + b * MCAP + pos] = ii;
      }
    }
  }
}

// Gather anchor embedding (first-CP row) per segment; zero rows for no-cp segs.
__global__ __launch_bounds__(256) void k_anchor(const float* __restrict__ embed,
                                                float* wsf, int* wsi) {
  const int b = blockIdx.x;
  const int t = threadIdx.x;
  const int cnt = wsi[OFF_CNT + b * Kk + t];
  const int fi = wsi[OFF_FIRST + b * Kk + t];
  float4* dst = (float4*)(wsf + OFF_ANCH + ((size_t)b * Kk + t) * Dd);
  if (cnt > 0) {
    const float4* src = (const float4*)(embed + ((size_t)b * Nn + (size_t)fi) * Dd);
    dst[0] = src[0]; dst[1] = src[1]; dst[2] = src[2]; dst[3] = src[3];
  } else {
    float4 z = make_float4(0.f, 0.f, 0.f, 0.f);
    dst[0] = z; dst[1] = z; dst[2] = z; dst[3] = z;
  }
}

// Main pass: scalars + direct per-point d2 against LDS anchors.
// Only 2 LDS atomics per point (vs 18 before).
__global__ __launch_bounds__(256) void k_pass(const float* __restrict__ beta,
                                              const int* __restrict__ sid,
                                              const void* __restrict__ cpp,
                                              const float* __restrict__ embed,
                                              float* wsf, int* wsi, int use_part) {
  const int b = blockIdx.y;
  const int ch = blockIdx.x;
  const int tid = threadIdx.x;
  __shared__ float ls_anch[Kk * ASTR];
  __shared__ float ls_d2[Kk];
  __shared__ int ls_inst[Kk];
  __shared__ float sred[4][8];
  // stage anchors: thread t copies row t into stride-20 LDS
  {
    const float4* src = (const float4*)(wsf + OFF_ANCH + ((size_t)b * Kk + tid) * Dd);
    float4 v0 = src[0], v1 = src[1], v2 = src[2], v3 = src[3];
    float4* d = (float4*)&ls_anch[tid * ASTR];
    d[0] = v0; d[1] = v1; d[2] = v2; d[3] = v3;
  }
  ls_d2[tid] = 0.f;
  ls_inst[tid] = 0;
  __syncthreads();
  const int mode = wsi[OFF_MODE];
  const int base = b * Nn;
  const float* eb = embed + (size_t)base * Dd;
  float a0 = 0.f, a1 = 0.f, a2 = 0.f, a3 = 0.f, a4 = 0.f, a5 = 0.f;
  for (int it = 0; it < CHUNK / 1024; ++it) {
    const int i0 = ch * CHUNK + it * 1024 + tid * 4;
    int4 s4 = *(const int4*)(sid + base + i0);
    float4 b4 = *(const float4*)(beta + base + i0);
    unsigned int cpw[4];
    if (mode) {
      unsigned int u = ((const unsigned int*)cpp)[(base + i0) >> 2];
      cpw[0] = u & 0xffu; cpw[1] = (u >> 8) & 0xffu;
      cpw[2] = (u >> 16) & 0xffu; cpw[3] = u >> 24;
    } else {
      uint4 u = ((const uint4*)cpp)[(base + i0) >> 2];
      cpw[0] = u.x; cpw[1] = u.y; cpw[2] = u.z; cpw[3] = u.w;
    }
    float4 ev[16];
    #pragma unroll
    for (int q = 0; q < 16; ++q)
      ev[q] = *(const float4*)(eb + (size_t)(i0 + (q >> 2)) * Dd + (q & 3) * 4);
    const int ss[4] = {s4.x, s4.y, s4.z, s4.w};
    const float xs[4] = {b4.x, b4.y, b4.z, b4.w};
    #pragma unroll
    for (int j = 0; j < 4; ++j) {
      const int s = ss[j];
      const bool cp = cpw[j] != 0u;
      const float x = xs[j];
      const float p = 1.f / (1.f + __expf(-x));
      const float sp = __logf(1.f + __expf(-fabsf(x)));
      const float ce0 = sp + fmaxf(x, 0.f);
      if (cp) { a1 += fmaxf(0.8f - p, 0.f); a4 += 1.f; }
      else    { a0 += ce0; a2 += fmaxf(p - 0.2f, 0.f); }
      if (s == -1) { a3 += ce0; a5 += 1.f; }
      // d2 against anchor (clamped row for invalid s; masked at the atomic)
      const int sc = s >= 0 ? s : 0;
      const float4* ar = (const float4*)&ls_anch[sc * ASTR];
      float4 A0 = ar[0], A1 = ar[1], A2 = ar[2], A3 = ar[3];
      float4 v0 = ev[j * 4], v1 = ev[j * 4 + 1], v2 = ev[j * 4 + 2], v3 = ev[j * 4 + 3];
      float d2 = 0.f, df;
      df = v0.x - A0.x; d2 += df * df;  df = v0.y - A0.y; d2 += df * df;
      df = v0.z - A0.z; d2 += df * df;  df = v0.w - A0.w; d2 += df * df;
      df = v1.x - A1.x; d2 += df * df;  df = v1.y - A1.y; d2 += df * df;
      df = v1.z - A1.z; d2 += df * df;  df = v1.w - A1.w; d2 += df * df;
      df = v2.x - A2.x; d2 += df * df;  df = v2.y - A2.y; d2 += df * df;
      df = v2.z - A2.z; d2 += df * df;  df = v2.w - A2.w; d2 += df * df;
      df = v3.x - A3.x; d2 += df * df;  df = v3.y - A3.y; d2 += df * df;
      df = v3.z - A3.z; d2 += df * df;  df = v3.w - A3.w; d2 += df * df;
      if (s >= 0) {
        atomicAdd(&ls_inst[s], 1);
        atomicAdd(&ls_d2[s], d2);   // no-cp segs accumulate junk vs zero anchor; k_event ignores them
      }
    }
  }
  __syncthreads();
  if (use_part) {
    float2* pb = (float2*)(wsf + OFF_PART + (((size_t)(b * NCH + ch)) * Kk + tid) * 2);
    *pb = make_float2(ls_d2[tid], (float)ls_inst[tid]);
  } else {
    atomicAdd(&wsf[OFF_D2 + b * Kk + tid], ls_d2[tid]);
    atomicAdd(&wsi[OFF_INST + b * Kk + tid], ls_inst[tid]);
  }
  // block scalar reduce
  for (int o = 32; o > 0; o >>= 1) {
    a0 += __shfl_down(a0, o); a1 += __shfl_down(a1, o); a2 += __shfl_down(a2, o);
    a3 += __shfl_down(a3, o); a4 += __shfl_down(a4, o); a5 += __shfl_down(a5, o);
  }
  const int wv = tid >> 6;
  if ((tid & 63) == 0) {
    sred[wv][0] = a0; sred[wv][1] = a1; sred[wv][2] = a2;
    sred[wv][3] = a3; sred[wv][4] = a4; sred[wv][5] = a5;
  }
  __syncthreads();
  if (tid == 0) {
    float s0 = 0, s1 = 0, s2 = 0, s3 = 0, s4 = 0, s5 = 0;
    for (int q = 0; q < 4; ++q) {
      s0 += sred[q][0]; s1 += sred[q][1]; s2 += sred[q][2];
      s3 += sred[q][3]; s4 += sred[q][4]; s5 += sred[q][5];
    }
    atomicAdd(&wsf[OFF_SCAL + b * 32 + 0], s0);
    atomicAdd(&wsf[OFF_SCAL + b * 32 + 1], s1);
    atomicAdd(&wsf[OFF_SCAL + b * 32 + 2], s2);
    atomicAdd(&wsf[OFF_SCAL + b * 32 + 3], s3);
    atomicAdd(&wsf[OFF_SCAL + b * 32 + 4], s4);
    atomicAdd(&wsf[OFF_SCAL + b * 32 + 5], s5);
  }
}

__global__ __launch_bounds__(256) void k_reduce(float* wsf, int* wsi) {
  const int g = blockIdx.x * 256 + threadIdx.x;   // [0, B*K)
  const int b = g >> 8, seg = g & 255;
  const float2* p = (const float2*)(wsf + OFF_PART + (((size_t)b * NCH) * Kk + seg) * 2);
  float d2 = 0.f, inst = 0.f;
  for (int chh = 0; chh < NCH; ++chh) {
    float2 v = p[(size_t)chh * Kk];
    d2 += v.x; inst += v.y;
  }
  wsf[OFF_D2 + g] = d2;
  wsi[OFF_INST + g] = (int)(inst + 0.5f);
}

__global__ __launch_bounds__(256) void k_event(float* wsf, int* wsi) {
  const int b = blockIdx.x;
  const int t = threadIdx.x;
  const int cnt = wsi[OFF_CNT + b * Kk + t];
  const int inst = wsi[OFF_INST + b * Kk + t];
  const float sumf = wsf[OFF_SUMF + b * Kk + t];
  const float d2s = wsf[OFF_D2 + b * Kk + t];
  const bool has = cnt > 0;
  float attr_p = 0.f, w = 0.f, wf = 0.f;
  if (has) {
    const float instf = (float)inst;
    attr_p = d2s / fmaxf(instf, 1.f);
    w = instf;
    wf = instf * (sumf / fmaxf((float)cnt, 1.f));
  }
  for (int o = 32; o > 0; o >>= 1) {
    attr_p += __shfl_down(attr_p, o);
    w += __shfl_down(w, o);
    wf += __shfl_down(wf, o);
  }
  __shared__ float r3[3][4];
  if ((t & 63) == 0) { r3[0][t >> 6] = attr_p; r3[1][t >> 6] = w; r3[2][t >> 6] = wf; }
  __syncthreads();
  if (t == 0) {
    float at = r3[0][0] + r3[0][1] + r3[0][2] + r3[0][3];
    float sw = r3[1][0] + r3[1][1] + r3[1][2] + r3[1][3];
    float swf = r3[2][0] + r3[2][1] + r3[2][2] + r3[2][3];
    float pos_bce = swf / fmaxf(sw, 1.f);
    float* sc = wsf + OFF_SCAL + b * 32;
    float ce0n = sc[0], rpos = sc[1], rneg = sc[2], ce0b = sc[3], ncp = sc[4], nbg = sc[5];
    int mv = wsi[OFF_SCAL + b * 32 + 6];
    float nncp = (float)Nn - ncp;
    float neg_bce = nncp > 0.f ? ce0n / fmaxf(nncp, 1.f) : 0.f;
    float pos_m = rpos / fmaxf(ncp, 1.f);
    float neg_m = nncp > 0.f ? rneg / fmaxf(nncp, 1.f) : 0.f;
    float bg_bce = nbg > 0.f ? ce0b / fmaxf(nbg, 1.f) : 0.f;
    sc[8] = W_BPOS * pos_bce + W_BNEG * neg_bce + W_BBG * bg_bce + W_MARG * (pos_m + neg_m);
    sc[10] = at;
    float nvalid = (float)Nn - nbg;
    wsi[OFF_SCAL + b * 32 + 7] = (nvalid > 0.f && mv > 0) ? 1 : 0;
  }
}

__global__ __launch_bounds__(256) void k_rep(const float* __restrict__ embed,
                                             float* wsf, int* wsi) {
  const int b = blockIdx.y;
  const int t = threadIdx.x;
  __shared__ int sidx[MCAP];
  __shared__ float cemb[256 * CSTR];
  __shared__ float csq[256];
  __shared__ float red[4];
  const int mv = wsi[OFF_SCAL + b * 32 + 6];
  const int msel = mv < MSEL ? mv : MSEL;
  const int mload = mv < MCAP ? mv : MCAP;
  for (int i = t; i < MCAP; i += 256)
    sidx[i] = (i < mload) ? wsi[OFF_CPIDX + b * MCAP + i] : 0x7FFFFFFF;
  __syncthreads();
  if (mv > MSEL) {
    for (int ksz = 2; ksz <= MCAP; ksz <<= 1) {
      for (int j = ksz >> 1; j > 0; j >>= 1) {
        for (int e = t; e < MCAP; e += 256) {
          int ixj = e ^ j;
          if (ixj > e) {
            bool up = ((e & ksz) == 0);
            int x = sidx[e], y = sidx[ixj];
            if ((x > y) == up) { sidx[e] = y; sidx[ixj] = x; }
          }
        }
        __syncthreads();
      }
    }
  }
  const float* eb = embed + (size_t)b * Nn * Dd;
  const int row = blockIdx.x * 64 + (t & 63);
  const int cg = t >> 6;
  const bool rok = row < msel;
  float r[Dd];
  float rsq = 0.f;
  if (rok) {
    const float4* s = (const float4*)(eb + (size_t)sidx[row] * Dd);
    float4 v0 = s[0], v1 = s[1], v2 = s[2], v3 = s[3];
    r[0]=v0.x; r[1]=v0.y; r[2]=v0.z; r[3]=v0.w;
    r[4]=v1.x; r[5]=v1.y; r[6]=v1.z; r[7]=v1.w;
    r[8]=v2.x; r[9]=v2.y; r[10]=v2.z; r[11]=v2.w;
    r[12]=v3.x; r[13]=v3.y; r[14]=v3.z; r[15]=v3.w;
    #pragma unroll
    for (int d = 0; d < Dd; ++d) rsq += r[d] * r[d];
  }
  float acc = 0.f;
  for (int c0 = 0; c0 < msel; c0 += 256) {
    const int nc = (msel - c0) < 256 ? (msel - c0) : 256;
    __syncthreads();
    for (int wvi = t; wvi < nc * 4; wvi += 256) {
      int col = wvi >> 2, q = wvi & 3;
      float4 v = ((const float4*)(eb + (size_t)sidx[c0 + col] * Dd))[q];
      *(float4*)&cemb[col * CSTR + q * 4] = v;
    }
    __syncthreads();
    for (int col = t; col < nc; col += 256) {
      float s = 0.f;
      #pragma unroll
      for (int d = 0; d < Dd; ++d) s += cemb[col * CSTR + d] * cemb[col * CSTR + d];
      csq[col] = s;
    }
    __syncthreads();
    if (rok) {
      for (int c = cg; c < nc; c += 4) {
        float dotrc = 0.f;
        #pragma unroll
        for (int d = 0; d < Dd; ++d) dotrc += r[d] * cemb[c * CSTR + d];
        acc += __expf(2.f * dotrc - rsq - csq[c]);
      }
    }
  }
  for (int o = 32; o > 0; o >>= 1) acc += __shfl_down(acc, o);
  if ((t & 63) == 0) red[t >> 6] = acc;
  __syncthreads();
  if (t == 0) {
    float s = red[0] + red[1] + red[2] + red[3];
    if (s != 0.f) atomicAdd(&wsf[OFF_SCAL + b * 32 + 9], s);
  }
}

__global__ void k_final(float* wsf, int* wsi, float* out, int out_size) {
  const int t = threadIdx.x;
  if (t == 0) {
    float total = 0.f;
    int cnt = 0;
    for (int b = 0; b < Bn; ++b) {
      float* sc = wsf + OFF_SCAL + b * 32;
      int* sci = wsi + OFF_SCAL + b * 32;
      int mv = sci[6];
      if (sci[7]) {
        float mvf = (float)mv;
        float rep = (mv > 1) ? W_REP * sc[9] / fmaxf(mvf * mvf, 1.f) : 0.f;
        total += sc[8] + W_ATTR * sc[10] + rep;
        cnt++;
      }
    }
    out[0] = (cnt > 0) ? total / (float)cnt : 0.f;
  }
  for (int i = 1 + t; i < out_size; i += 256) out[i] = 0.f;
}

extern "C" void kernel_launch(void* const* d_in, const int* in_sizes, int n_in,
                              void* d_out, int out_size, void* d_ws, size_t ws_size,
                              hipStream_t stream) {
  const float* beta = (const float*)d_in[0];
  const float* embed = (const float*)d_in[1];
  const int* sid = (const int*)d_in[2];
  const void* cp = d_in[3];
  float* out = (float*)d_out;
  float* wsf = (float*)d_ws;
  int* wsi = (int*)d_ws;
  const int use_part = ws_size >= WS_NEEDED ? 1 : 0;

  hipMemsetAsync(d_ws, 0, (size_t)ZERO_WORDS * 4, stream);
  hipMemsetAsync((char*)d_ws + (size_t)OFF_FIRST * 4, 0x7F, (size_t)Bn * Kk * 4, stream);
  k_detect<<<256, 256, 0, stream>>>((const unsigned int*)cp, wsi);
  k_cplist<<<2048, 256, 0, stream>>>(beta, sid, cp, wsf, wsi);
  k_anchor<<<Bn, 256, 0, stream>>>(embed, wsf, wsi);
  dim3 gp(NCH, Bn);
  k_pass<<<gp, 256, 0, stream>>>(beta, sid, cp, embed, wsf, wsi, use_part);
  if (use_part) k_reduce<<<(Bn * Kk) / 256, 256, 0, stream>>>(wsf, wsi);
  k_event<<<Bn, 256, 0, stream>>>(wsf, wsi);
  dim3 gr(MSEL / 64, Bn);
  k_rep<<<gr, 256, 0, stream>>>(embed, wsf, wsi);
  k_final<<<1, 256, 0, stream>>>(wsf, wsi, out, out_size);
}